// Round 3
// baseline (371.947 us; speedup 1.0000x reference)
//
#include <hip/hip_runtime.h>

// out[i] = (a+d) + sqrt(|a*d - b*c|) per contiguous 2x2 fp32 block.
// 4 rows/thread: 64 B read (4x dwordx4), 16 B vector store. Non-temporal
// hints: pure streaming, zero reuse (input = 256 MiB = exactly L3 size).
// Use a Clang native vector type — __builtin_nontemporal_* rejects
// HIP_vector_type structs.
typedef float vfloat4 __attribute__((ext_vector_type(4)));

__global__ __launch_bounds__(256)
void MyModel_61933428415478_kernel(const vfloat4* __restrict__ x,
                                   vfloat4* __restrict__ out, int n4) {
    int i = blockIdx.x * blockDim.x + threadIdx.x;
    if (i < n4) {
        const vfloat4* p = x + (size_t)4 * i;
        vfloat4 v0 = __builtin_nontemporal_load(p + 0);
        vfloat4 v1 = __builtin_nontemporal_load(p + 1);
        vfloat4 v2 = __builtin_nontemporal_load(p + 2);
        vfloat4 v3 = __builtin_nontemporal_load(p + 3);
        vfloat4 r;
        r.x = (v0.x + v0.w) + sqrtf(fabsf(v0.x * v0.w - v0.y * v0.z));
        r.y = (v1.x + v1.w) + sqrtf(fabsf(v1.x * v1.w - v1.y * v1.z));
        r.z = (v2.x + v2.w) + sqrtf(fabsf(v2.x * v2.w - v2.y * v2.z));
        r.w = (v3.x + v3.w) + sqrtf(fabsf(v3.x * v3.w - v3.y * v3.z));
        __builtin_nontemporal_store(r, out + i);
    }
}

// Scalar tail fallback (n not divisible by 4) — unused for N=16777216 but safe.
__global__ __launch_bounds__(256)
void MyModel_61933428415478_tail(const vfloat4* __restrict__ x,
                                 float* __restrict__ out, int start, int n) {
    int i = start + blockIdx.x * blockDim.x + threadIdx.x;
    if (i < n) {
        vfloat4 v = x[i];
        out[i] = (v.x + v.w) + sqrtf(fabsf(v.x * v.w - v.y * v.z));
    }
}

extern "C" void kernel_launch(void* const* d_in, const int* in_sizes, int n_in,
                              void* d_out, int out_size, void* d_ws, size_t ws_size,
                              hipStream_t stream) {
    const vfloat4* x = (const vfloat4*)d_in[0];
    int n = in_sizes[0] >> 2;   // number of 2x2 rows
    int n4 = n >> 2;            // rows processed 4-at-a-time
    int block = 256;
    if (n4 > 0) {
        int grid = (n4 + block - 1) / block;
        MyModel_61933428415478_kernel<<<grid, block, 0, stream>>>(
            x, (vfloat4*)d_out, n4);
    }
    int done = n4 << 2;
    if (done < n) {
        int rem = n - done;
        int grid = (rem + block - 1) / block;
        MyModel_61933428415478_tail<<<grid, block, 0, stream>>>(
            x, (float*)d_out, done, n);
    }
}

// Round 4
// 370.869 us; speedup vs baseline: 1.0029x; 1.0029x over previous
//
#include <hip/hip_runtime.h>

// out[i] = (a+d) + sqrt(|a*d - b*c|) per contiguous 2x2 fp32 block.
// 4 rows/thread: 64 B read (4x dwordx4), 16 B vector store.
// PLAIN loads: harness restores d_in right before the timed launch, so much
// of the 256 MiB input is L3-resident — cached loads harvest that (nt loads
// regressed 356->372 us by forcing HBM). NT only on the store: output is
// never re-read in-window, keep it from displacing input lines in L3.
typedef float vfloat4 __attribute__((ext_vector_type(4)));

__global__ __launch_bounds__(256)
void MyModel_61933428415478_kernel(const vfloat4* __restrict__ x,
                                   vfloat4* __restrict__ out, int n4) {
    int i = blockIdx.x * blockDim.x + threadIdx.x;
    if (i < n4) {
        const vfloat4* p = x + (size_t)4 * i;
        vfloat4 v0 = p[0];
        vfloat4 v1 = p[1];
        vfloat4 v2 = p[2];
        vfloat4 v3 = p[3];
        vfloat4 r;
        r.x = (v0.x + v0.w) + sqrtf(fabsf(v0.x * v0.w - v0.y * v0.z));
        r.y = (v1.x + v1.w) + sqrtf(fabsf(v1.x * v1.w - v1.y * v1.z));
        r.z = (v2.x + v2.w) + sqrtf(fabsf(v2.x * v2.w - v2.y * v2.z));
        r.w = (v3.x + v3.w) + sqrtf(fabsf(v3.x * v3.w - v3.y * v3.z));
        __builtin_nontemporal_store(r, out + i);
    }
}

// Scalar tail fallback (n not divisible by 4) — unused for N=16777216 but safe.
__global__ __launch_bounds__(256)
void MyModel_61933428415478_tail(const vfloat4* __restrict__ x,
                                 float* __restrict__ out, int start, int n) {
    int i = start + blockIdx.x * blockDim.x + threadIdx.x;
    if (i < n) {
        vfloat4 v = x[i];
        out[i] = (v.x + v.w) + sqrtf(fabsf(v.x * v.w - v.y * v.z));
    }
}

extern "C" void kernel_launch(void* const* d_in, const int* in_sizes, int n_in,
                              void* d_out, int out_size, void* d_ws, size_t ws_size,
                              hipStream_t stream) {
    const vfloat4* x = (const vfloat4*)d_in[0];
    int n = in_sizes[0] >> 2;   // number of 2x2 rows
    int n4 = n >> 2;            // rows processed 4-at-a-time
    int block = 256;
    if (n4 > 0) {
        int grid = (n4 + block - 1) / block;
        MyModel_61933428415478_kernel<<<grid, block, 0, stream>>>(
            x, (vfloat4*)d_out, n4);
    }
    int done = n4 << 2;
    if (done < n) {
        int rem = n - done;
        int grid = (rem + block - 1) / block;
        MyModel_61933428415478_tail<<<grid, block, 0, stream>>>(
            x, (float*)d_out, done, n);
    }
}

// Round 5
// 355.311 us; speedup vs baseline: 1.0468x; 1.0438x over previous
//
#include <hip/hip_runtime.h>

// out[i] = (a+d) + sqrt(|a*d - b*c|) for each contiguous 2x2 fp32 block.
// Memory-bound streaming: 16 B read + 4 B write per row, zero reuse.
// Measured best config (R1: 356 us window): 1 row/thread, plain float4
// load (16 B/lane coalescing sweet spot), plain scalar store. NT hints
// and 4-row unrolling measured neutral-to-worse (R3/R4: ~371 us) —
// window HBM bytes are invariant, so keep the simplest form.
__global__ __launch_bounds__(256)
void MyModel_61933428415478_kernel(const float4* __restrict__ x,
                                   float* __restrict__ out, int n) {
    int i = blockIdx.x * blockDim.x + threadIdx.x;
    if (i < n) {
        float4 v = x[i];                      // v.x=a v.y=b v.z=c v.w=d
        float det = v.x * v.w - v.y * v.z;
        out[i] = (v.x + v.w) + sqrtf(fabsf(det));
    }
}

extern "C" void kernel_launch(void* const* d_in, const int* in_sizes, int n_in,
                              void* d_out, int out_size, void* d_ws, size_t ws_size,
                              hipStream_t stream) {
    const float4* x = (const float4*)d_in[0];
    float* out = (float*)d_out;
    int n = in_sizes[0] >> 2;                 // flat count / 4 = number of 2x2 rows
    int block = 256;
    int grid = (n + block - 1) / block;
    MyModel_61933428415478_kernel<<<grid, block, 0, stream>>>(x, out, n);
}